// Round 12
// baseline (137.684 us; speedup 1.0000x reference)
//
#include <hip/hip_runtime.h>
#include <math.h>

// Fused HENN MLP: gather -> segment_sum -> Linear(256,256)+ReLU -> Linear(256,1) -> sigmoid
//
// R12 pipeline (3 launches):
//  1. prep (fused):  x->bf16 (nt loads), W1->bf16, seg_ptr build   [R7 verbatim]
//  2. henn_gather:   R7 engine VERBATIM — service/delivery-pinned at 6.1 TB/s
//                    logical (97% of streaming ceiling); not touchable.
//  3. henn_mlp3:     PERSISTENT double-buffered MLP. 512 blocks (2/CU), each
//                    loops tiles of 64 segments stride-512. Per iter:
//                    issue next tile's 8 u4 nt loads (regs, T14 split) ->
//                    compute current tile from LDS (M=64 MFMA, nt-half split,
//                    R7-verified layout) -> barrier -> out-store + ds_write
//                    staged regs to other buffer -> barrier. Zg stage latency
//                    hides under compute; no per-tile block ramp.
//
// Falls back to the R4-style fused f32 kernel if ws_size is too small.

typedef __attribute__((ext_vector_type(8))) short bf16x8;
typedef __attribute__((ext_vector_type(4))) float f32x4;
typedef __attribute__((ext_vector_type(4))) float f4;
typedef __attribute__((ext_vector_type(4))) unsigned u4;
typedef __attribute__((ext_vector_type(2))) unsigned u2;

__device__ __forceinline__ ushort f2bf(float f) {   // RNE f32->bf16
  unsigned u = __float_as_uint(f);
  return (ushort)((u + 0x7FFF + ((u >> 16) & 1)) >> 16);
}
__device__ __forceinline__ unsigned pack2(float lo, float hi) {
  return (unsigned)f2bf(lo) | ((unsigned)f2bf(hi) << 16);
}

#define PREP_CONVX_BLOCKS 2048
#define PREP_W1_BLOCKS    64
#define MLP_G             512

__global__ __launch_bounds__(256) void prep(
    const float* __restrict__ x, ushort* __restrict__ xb, long nx,
    const float* __restrict__ W1, ushort* __restrict__ W1b,
    const int* __restrict__ tids, int* __restrict__ ptr, int P, int E,
    int do_convx)
{
  const int b = blockIdx.x;
  if (b < PREP_CONVX_BLOCKS) {
    if (!do_convx) return;
    long i = ((long)b * 256 + threadIdx.x) * 8;
    const long stride = (long)PREP_CONVX_BLOCKS * 256 * 8;
    for (; i < nx; i += stride) {
      const f4 v0 = __builtin_nontemporal_load((const f4*)(x + i));
      const f4 v1 = __builtin_nontemporal_load((const f4*)(x + i + 4));
      u4 o;
      o.x = pack2(v0.x, v0.y); o.y = pack2(v0.z, v0.w);
      o.z = pack2(v1.x, v1.y); o.w = pack2(v1.z, v1.w);
      *(u4*)(xb + i) = o;                      // keep xb cacheable (hot buffer)
    }
  } else if (b < PREP_CONVX_BLOCKS + PREP_W1_BLOCKS) {
    const int base = ((b - PREP_CONVX_BLOCKS) * 256 + threadIdx.x) * 4;
    if (base < 256 * 256) {
      const f4 v = *(const f4*)(W1 + base);
      u2 o; o.x = pack2(v.x, v.y); o.y = pack2(v.z, v.w);
      *(u2*)(W1b + base) = o;
    }
  } else {
    const int p = (b - PREP_CONVX_BLOCKS - PREP_W1_BLOCKS) * 256 + threadIdx.x;
    if (p >= P) return;
    const int v = tids[p];
    const int prev = (p == 0) ? -1 : tids[p - 1];
    for (int e = prev + 1; e <= v; ++e) ptr[e] = p;
    if (p == P - 1) {
      for (int e = v + 1; e <= E; ++e) ptr[e] = P;
    }
  }
}

__global__ __launch_bounds__(128, 8) void henn_gather(
    const ushort* __restrict__ xb,
    const int* __restrict__ tnodes,
    const int* __restrict__ ptr,
    ushort* __restrict__ Zg,
    int E)
{
  const int lane = threadIdx.x & 63;
  const int wid  = threadIdx.x >> 6;             // 0..1
  const int e0   = blockIdx.x * 16 + wid * 8;    // this wave's 8 segments
  if (e0 >= E) return;
  const int nseg = min(8, E - e0);

  int bnd = 0;
  if (lane <= 8) bnd = ptr[min(e0 + lane, E)];   // bounds for segs e0..e0+8
  const int plo = __builtin_amdgcn_readfirstlane(__shfl(bnd, 0));
  const int phi = __builtin_amdgcn_readfirstlane(__shfl(bnd, nseg));
  const int total = phi - plo;                   // SGPR

  const char* xbB = (const char*)xb;
  const int lb = lane * 8;                       // byte offset within 512B row
  char* zB = (char*)Zg + (size_t)e0 * 512 + lb;

  float a0 = 0.f, a1 = 0.f, a2 = 0.f, a3 = 0.f;
  int s = 0;
  int hi_s = __builtin_amdgcn_readfirstlane(__shfl(bnd, 1));

#define FLUSHCHK(PCUR)                                                        \
  while ((PCUR) >= hi_s) {            /* wave-uniform segment flush */        \
    u2 oz; oz.x = pack2(a0, a1); oz.y = pack2(a2, a3);                        \
    __builtin_nontemporal_store(oz, (u2*)(zB + (size_t)s * 512));             \
    a0 = a1 = a2 = a3 = 0.f;                                                  \
    ++s; hi_s = __builtin_amdgcn_readfirstlane(__shfl(bnd, min(s + 1, 8)));   \
  }

#define ACCV(V)                                                               \
  a0 += __uint_as_float((V).x << 16);                                         \
  a1 += __uint_as_float((V).x & 0xffff0000u);                                 \
  a2 += __uint_as_float((V).y << 16);                                         \
  a3 += __uint_as_float((V).y & 0xffff0000u);

  if (total > 0) {
    const int tmax = total - 1;
    u2 va[8], vb[8];
    // prologue: fill both banks; indices wave-uniform -> tnodes via s_load
#pragma unroll
    for (int k = 0; k < 8; ++k) {
      const int p = plo + min(k, tmax);
      va[k] = *(const u2*)(xbB + (size_t)tnodes[p] * 512 + lb);
    }
#pragma unroll
    for (int k = 0; k < 8; ++k) {
      const int p = plo + min(8 + k, tmax);
      vb[k] = *(const u2*)(xbB + (size_t)tnodes[p] * 512 + lb);
    }

    for (int j = 0; j < total; j += 16) {
      // consume bank A (pairs j..j+8)
#pragma unroll
      for (int k = 0; k < 8; ++k) {
        const int pc = j + k;
        if (pc < total) { FLUSHCHK(plo + pc) ACCV(va[k]) }
      }
      // refill bank A for pairs [j+16, j+24)
#pragma unroll
      for (int k = 0; k < 8; ++k) {
        const int p = plo + min(j + 16 + k, tmax);
        va[k] = *(const u2*)(xbB + (size_t)tnodes[p] * 512 + lb);
      }
      // consume bank B (pairs j+8..j+16)
#pragma unroll
      for (int k = 0; k < 8; ++k) {
        const int pc = j + 8 + k;
        if (pc < total) { FLUSHCHK(plo + pc) ACCV(vb[k]) }
      }
      // refill bank B for pairs [j+24, j+32)
#pragma unroll
      for (int k = 0; k < 8; ++k) {
        const int p = plo + min(j + 24 + k, tmax);
        vb[k] = *(const u2*)(xbB + (size_t)tnodes[p] * 512 + lb);
      }
    }
  }
  // flush remaining segments (incl. trailing empties)
  while (s < nseg) {
    u2 oz; oz.x = pack2(a0, a1); oz.y = pack2(a2, a3);
    __builtin_nontemporal_store(oz, (u2*)(zB + (size_t)s * 512));
    a0 = a1 = a2 = a3 = 0.f;
    ++s;
  }
#undef FLUSHCHK
#undef ACCV
}

// R12: persistent double-buffered MLP. 64 segs/tile, 2x32KB LDS, 512 blocks.
__global__ __launch_bounds__(256) void henn_mlp3(
    const ushort* __restrict__ Zg,
    const ushort* __restrict__ W1b,
    const float* __restrict__ b1,
    const float* __restrict__ W2,
    const float* __restrict__ b2,
    float* __restrict__ out,
    int E, int T)
{
  __shared__ __align__(16) ushort Zb[2][64 * 256];   // 2 x 32 KB, XOR-swizzled
  __shared__ float red[4 * 64];                      // 1 KB epilogue scratch
  const int tid  = threadIdx.x;
  const int wid  = tid >> 6;            // 0..3
  const int lane = tid & 63;
  const int l15  = lane & 15;
  const int l4   = lane >> 4;
  const int n0   = wid * 64;            // wave's h-slice

  int t = blockIdx.x;
  if (t >= T) return;

  // prologue: stage tile t into buffer 0 (swizzled ds_write)
  {
    const char* src = (const char*)Zg + (size_t)t * 32768;
#pragma unroll
    for (int i = 0; i < 8; ++i) {
      const int off = i * 4096 + tid * 16;
      const u4 v = __builtin_nontemporal_load((const u4*)(src + off));
      const int row = off >> 9;
      *(u4*)((char*)Zb[0] + (off ^ ((row & 7) << 4))) = v;
    }
  }
  __syncthreads();

  int cur = 0;
  for (; t < T; t += MLP_G, cur ^= 1) {
    // ---- issue next tile's loads early (T14: issue-early / write-late) ----
    u4 st0, st1, st2, st3, st4, st5, st6, st7;
    const int tn = t + MLP_G;
    const bool has_next = (tn < T);
    if (has_next) {
      const char* src = (const char*)Zg + (size_t)tn * 32768;
      st0 = __builtin_nontemporal_load((const u4*)(src + 0 * 4096 + tid * 16));
      st1 = __builtin_nontemporal_load((const u4*)(src + 1 * 4096 + tid * 16));
      st2 = __builtin_nontemporal_load((const u4*)(src + 2 * 4096 + tid * 16));
      st3 = __builtin_nontemporal_load((const u4*)(src + 3 * 4096 + tid * 16));
      st4 = __builtin_nontemporal_load((const u4*)(src + 4 * 4096 + tid * 16));
      st5 = __builtin_nontemporal_load((const u4*)(src + 5 * 4096 + tid * 16));
      st6 = __builtin_nontemporal_load((const u4*)(src + 6 * 4096 + tid * 16));
      st7 = __builtin_nontemporal_load((const u4*)(src + 7 * 4096 + tid * 16));
    }

    // ---- compute tile t from Zb[cur]: Y=relu(Z@W1^T+b1); pacc += W2.*Y ----
    const char* zb = (const char*)Zb[cur];
    float pacc[4][4];
#pragma unroll
    for (int mt = 0; mt < 4; ++mt)
#pragma unroll
      for (int r = 0; r < 4; ++r) pacc[mt][r] = 0.f;

#pragma unroll
    for (int half = 0; half < 2; ++half) {
      f32x4 acc[4][2];
#pragma unroll
      for (int mt = 0; mt < 4; ++mt)
#pragma unroll
        for (int nt = 0; nt < 2; ++nt)
          acc[mt][nt] = (f32x4){0.f, 0.f, 0.f, 0.f};

#pragma unroll
      for (int kk = 0; kk < 8; ++kk) {
        bf16x8 a[4];
#pragma unroll
        for (int mt = 0; mt < 4; ++mt) {
          const int row = mt * 16 + l15;
          const int raddr = row * 512 + kk * 64 + l4 * 16;
          a[mt] = *(const bf16x8*)(zb + (raddr ^ ((row & 7) << 4)));
        }
#pragma unroll
        for (int nt = 0; nt < 2; ++nt) {
          const int h = n0 + (half * 2 + nt) * 16 + l15;
          const bf16x8 b = *(const bf16x8*)(W1b + (size_t)h * 256 + kk * 32 + l4 * 8);
#pragma unroll
          for (int mt = 0; mt < 4; ++mt)
            acc[mt][nt] = __builtin_amdgcn_mfma_f32_16x16x32_bf16(a[mt], b, acc[mt][nt], 0, 0, 0);
        }
      }
#pragma unroll
      for (int nt = 0; nt < 2; ++nt) {
        const int h = n0 + (half * 2 + nt) * 16 + l15;
        const float b1h = b1[h];
        const float w2h = W2[h];
#pragma unroll
        for (int mt = 0; mt < 4; ++mt)
#pragma unroll
          for (int r = 0; r < 4; ++r) {
            const float y = acc[mt][nt][r] + b1h;
            pacc[mt][r] = fmaf(w2h, fmaxf(y, 0.f), pacc[mt][r]);
          }
      }
    }

    // ---- per-wave partials into red ----
#pragma unroll
    for (int mt = 0; mt < 4; ++mt) {
#pragma unroll
      for (int r = 0; r < 4; ++r) {
        float p = pacc[mt][r];
        p += __shfl_xor(p, 1);
        p += __shfl_xor(p, 2);
        p += __shfl_xor(p, 4);
        p += __shfl_xor(p, 8);
        if (l15 == 0) red[wid * 64 + mt * 16 + l4 * 4 + r] = p;
      }
    }
    __syncthreads();   // red visible; all Zb[cur] reads complete

    // ---- out store + write staged regs into the other buffer ----
    if (tid < 64) {
      const int e = t * 64 + tid;
      if (e < E) {
        const float v = red[tid] + red[64 + tid] + red[128 + tid] + red[192 + tid] + b2[0];
        out[e] = 1.f / (1.f + expf(-v));
      }
    }
    if (has_next) {
      char* dst = (char*)Zb[cur ^ 1];
#pragma unroll
      for (int i = 0; i < 8; ++i) {
        const int off = i * 4096 + tid * 16;
        const int row = off >> 9;
        u4 v;
        switch (i) {
          case 0: v = st0; break; case 1: v = st1; break;
          case 2: v = st2; break; case 3: v = st3; break;
          case 4: v = st4; break; case 5: v = st5; break;
          case 6: v = st6; break; default: v = st7; break;
        }
        *(u4*)(dst + (off ^ ((row & 7) << 4))) = v;
      }
    }
    __syncthreads();   // staging visible for next iteration
  }
}

// ---------------- R4 fused fallback (ws too small for split path) ----------
__global__ __launch_bounds__(256, 4) void henn_main(
    const float* __restrict__ x,
    const int* __restrict__ tnodes,
    const int* __restrict__ ptr,
    const ushort* __restrict__ W1b,
    const float* __restrict__ b1,
    const float* __restrict__ W2,
    const float* __restrict__ b2,
    float* __restrict__ out,
    int E)
{
  __shared__ __align__(16) ushort Zb[64 * 256];
  const int tid  = threadIdx.x;
  const int wid  = tid >> 6;
  const int lane = tid & 63;
  const int l15  = lane & 15;
  const int l4   = lane >> 4;
  const int e0   = blockIdx.x * 64;

  int bidx = e0 + wid * 16 + lane;
  int bnd = 0;
  if (lane < 17) bnd = ptr[min(bidx, E)];

  for (int s = 0; s < 16; ++s) {
    const int lo = __shfl(bnd, s);
    const int hi = __shfl(bnd, s + 1);
    float4 a0 = {0,0,0,0}, a1 = {0,0,0,0}, a2 = {0,0,0,0}, a3 = {0,0,0,0};
    for (int base = lo; base < hi; base += 64) {
      const int cnt = min(64, hi - base);
      const int nd = (lane < cnt) ? tnodes[base + lane] : 0;
      const int rounds = (cnt + 3) >> 2;
      for (int r = 0; r < rounds; ++r) {
        const int idx = r * 4 + l4;
        const int node = __shfl(nd, min(idx, cnt - 1));
        if (idx < cnt) {
          const float4* rowp = (const float4*)(x + (size_t)node * 256) + l15;
          const float4 v0 = rowp[0];
          const float4 v1 = rowp[16];
          const float4 v2 = rowp[32];
          const float4 v3 = rowp[48];
          a0.x += v0.x; a0.y += v0.y; a0.z += v0.z; a0.w += v0.w;
          a1.x += v1.x; a1.y += v1.y; a1.z += v1.z; a1.w += v1.w;
          a2.x += v2.x; a2.y += v2.y; a2.z += v2.z; a2.w += v2.w;
          a3.x += v3.x; a3.y += v3.y; a3.z += v3.z; a3.w += v3.w;
        }
      }
    }
    a0.x += __shfl_xor(a0.x,16); a0.y += __shfl_xor(a0.y,16); a0.z += __shfl_xor(a0.z,16); a0.w += __shfl_xor(a0.w,16);
    a0.x += __shfl_xor(a0.x,32); a0.y += __shfl_xor(a0.y,32); a0.z += __shfl_xor(a0.z,32); a0.w += __shfl_xor(a0.w,32);
    a1.x += __shfl_xor(a1.x,16); a1.y += __shfl_xor(a1.y,16); a1.z += __shfl_xor(a1.z,16); a1.w += __shfl_xor(a1.w,16);
    a1.x += __shfl_xor(a1.x,32); a1.y += __shfl_xor(a1.y,32); a1.z += __shfl_xor(a1.z,32); a1.w += __shfl_xor(a1.w,32);
    a2.x += __shfl_xor(a2.x,16); a2.y += __shfl_xor(a2.y,16); a2.z += __shfl_xor(a2.z,16); a2.w += __shfl_xor(a2.w,16);
    a2.x += __shfl_xor(a2.x,32); a2.y += __shfl_xor(a2.y,32); a2.z += __shfl_xor(a2.z,32); a2.w += __shfl_xor(a2.w,32);
    a3.x += __shfl_xor(a3.x,16); a3.y += __shfl_xor(a3.y,16); a3.z += __shfl_xor(a3.z,16); a3.w += __shfl_xor(a3.w,16);
    a3.x += __shfl_xor(a3.x,32); a3.y += __shfl_xor(a3.y,32); a3.z += __shfl_xor(a3.z,32); a3.w += __shfl_xor(a3.w,32);
    float4 m = (l4 == 0) ? a0 : (l4 == 1) ? a1 : (l4 == 2) ? a2 : a3;
    const int row = wid * 16 + s;
    ushort4 o; o.x = f2bf(m.x); o.y = f2bf(m.y); o.z = f2bf(m.z); o.w = f2bf(m.w);
    const int waddr = row * 512 + lane * 8;
    *(ushort4*)((char*)Zb + (waddr ^ ((row & 7) << 4))) = o;
  }
  __syncthreads();

  const int n0 = wid * 64;
  f32x4 acc[4][4];
#pragma unroll
  for (int mt = 0; mt < 4; ++mt)
#pragma unroll
    for (int nt = 0; nt < 4; ++nt)
      acc[mt][nt] = (f32x4){0.f, 0.f, 0.f, 0.f};
#pragma unroll
  for (int kk = 0; kk < 8; ++kk) {
    bf16x8 a[4];
#pragma unroll
    for (int mt = 0; mt < 4; ++mt) {
      const int row = mt * 16 + l15;
      const int raddr = row * 512 + kk * 64 + l4 * 16;
      a[mt] = *(const bf16x8*)((const char*)Zb + (raddr ^ ((row & 7) << 4)));
    }
#pragma unroll
    for (int nt = 0; nt < 4; ++nt) {
      const int h = n0 + nt * 16 + l15;
      const bf16x8 b = *(const bf16x8*)(W1b + (size_t)h * 256 + kk * 32 + l4 * 8);
#pragma unroll
      for (int mt = 0; mt < 4; ++mt)
        acc[mt][nt] = __builtin_amdgcn_mfma_f32_16x16x32_bf16(a[mt], b, acc[mt][nt], 0, 0, 0);
    }
  }
  __syncthreads();

  float b1h[4], w2v[4];
#pragma unroll
  for (int nt = 0; nt < 4; ++nt) {
    const int h = n0 + nt * 16 + l15;
    b1h[nt] = b1[h];
    w2v[nt] = W2[h];
  }
  float* red = (float*)Zb;
#pragma unroll
  for (int mt = 0; mt < 4; ++mt) {
#pragma unroll
    for (int r = 0; r < 4; ++r) {
      float p = 0.f;
#pragma unroll
      for (int nt = 0; nt < 4; ++nt) {
        const float y = acc[mt][nt][r] + b1h[nt];
        p = fmaf(w2v[nt], fmaxf(y, 0.f), p);
      }
      p += __shfl_xor(p, 1);
      p += __shfl_xor(p, 2);
      p += __shfl_xor(p, 4);
      p += __shfl_xor(p, 8);
      if (l15 == 0) red[wid * 64 + mt * 16 + l4 * 4 + r] = p;
    }
  }
  __syncthreads();

  if (tid < 64) {
    const int e = e0 + tid;
    if (e < E) {
      const float v = red[tid] + red[64 + tid] + red[128 + tid] + red[192 + tid] + b2[0];
      out[e] = 1.f / (1.f + expf(-v));
    }
  }
}

extern "C" void kernel_launch(void* const* d_in, const int* in_sizes, int n_in,
                              void* d_out, int out_size, void* d_ws, size_t ws_size,
                              hipStream_t stream) {
  const float* x      = (const float*)d_in[0];
  const int*   tnodes = (const int*)d_in[1];
  const int*   tids   = (const int*)d_in[2];
  const float* W1     = (const float*)d_in[3];
  const float* b1     = (const float*)d_in[4];
  const float* W2     = (const float*)d_in[5];
  const float* b2     = (const float*)d_in[6];
  (void)n_in;

  const int P       = in_sizes[1];        // 800000
  const int E       = out_size;           // 100000
  const int n_nodes = in_sizes[0] / 256;  // 100000

  const size_t OFF_W1B  = 512 * 1024;
  const size_t OFF_XB   = 1024 * 1024;
  const size_t xb_bytes = (size_t)n_nodes * 512;
  const size_t off_zg   = OFF_XB + ((xb_bytes + 65535) & ~(size_t)65535);
  const size_t zg_bytes = (size_t)E * 512 + 65536;   // pad covers OOB tile rows
  const size_t need     = off_zg + zg_bytes;

  int*    seg_ptr = (int*)d_ws;
  ushort* W1b     = (ushort*)((char*)d_ws + OFF_W1B);
  ushort* xb      = (ushort*)((char*)d_ws + OFF_XB);
  ushort* Zg      = (ushort*)((char*)d_ws + off_zg);

  const int split_ok   = (ws_size >= need) ? 1 : 0;
  const int prep_grid  = PREP_CONVX_BLOCKS + PREP_W1_BLOCKS + (P + 255) / 256;
  prep<<<prep_grid, 256, 0, stream>>>(x, xb, (long)n_nodes * 256, W1, W1b,
                                      tids, seg_ptr, P, E, split_ok);

  if (split_ok) {
    const int gblocks = (E + 15) / 16;
    henn_gather<<<gblocks, 128, 0, stream>>>(xb, tnodes, seg_ptr, Zg, E);
    const int T = (E + 63) / 64;
    const int mblocks = (T < MLP_G) ? T : MLP_G;
    henn_mlp3<<<mblocks, 256, 0, stream>>>(Zg, W1b, b1, W2, b2, (float*)d_out, E, T);
  } else {
    const int blocks = (E + 63) / 64;
    henn_main<<<blocks, 256, 0, stream>>>(x, tnodes, seg_ptr, W1b, b1, W2, b2,
                                          (float*)d_out, E);
  }
}

// Round 13
// 125.399 us; speedup vs baseline: 1.0980x; 1.0980x over previous
//
#include <hip/hip_runtime.h>
#include <math.h>

// Fused HENN MLP: gather -> segment_sum -> Linear(256,256)+ReLU -> Linear(256,1) -> sigmoid
//
// R13 — algebraic restructure: segment_sum commutes with the linear layer,
//   segment_sum(gather(x)) @ W1^T  ==  segment_sum(gather(x @ W1^T))
// and N_NODES == N_EDGES, so the GEMM moves BEFORE the gather at equal FLOP
// cost. This deletes conv_x (conversion folds into GEMM staging), deletes the
// Zg round-trip (100 MB), and deletes the third MLP kernel (epilogue fuses
// into the gather's segment flush).
//
// Pipeline (3 launches):
//  1. prep2:      W1 f32->bf16 [256][256] + seg_ptr build (tiny)
//  2. gemm_h:     H = x @ W1^T, bf16 out. 64 nodes/block, 256 thr, 32KB LDS.
//                 Stage: f32 x tile -> bf16, XOR-swizzled (R7-verified layout).
//                 MFMA: R7-mlp structure verbatim (acc[4][4], K=256).
//                 Store: per-lane 2B scatter per verified C layout
//                 (row = mt*16 + l4*4 + r, col = n0 + nt*16 + l15).
//  3. gather_out: R7 gather engine verbatim (service-pinned at ~6.2 TB/s =
//                 98% of streaming ceiling) over H rows; per-segment flush is
//                 the FUSED epilogue: p = sum_c W2[c]*relu(hsum[c]+b1[c]) via
//                 preloaded per-lane coefficients + 6-shfl butterfly ->
//                 sigmoid -> out[e]. No Zg, no MLP kernel.
//
// Falls back to the R4-style fused f32 kernel if ws_size is too small.

typedef __attribute__((ext_vector_type(8))) short bf16x8;
typedef __attribute__((ext_vector_type(4))) float f32x4;
typedef __attribute__((ext_vector_type(4))) float f4;
typedef __attribute__((ext_vector_type(4))) unsigned u4;
typedef __attribute__((ext_vector_type(2))) unsigned u2;

__device__ __forceinline__ ushort f2bf(float f) {   // RNE f32->bf16
  unsigned u = __float_as_uint(f);
  return (ushort)((u + 0x7FFF + ((u >> 16) & 1)) >> 16);
}
__device__ __forceinline__ unsigned pack2(float lo, float hi) {
  return (unsigned)f2bf(lo) | ((unsigned)f2bf(hi) << 16);
}

#define PREP_W1_BLOCKS 64

__global__ __launch_bounds__(256) void prep2(
    const float* __restrict__ W1, ushort* __restrict__ W1b,
    const int* __restrict__ tids, int* __restrict__ ptr, int P, int E)
{
  const int b = blockIdx.x;
  if (b < PREP_W1_BLOCKS) {
    const int base = (b * 256 + threadIdx.x) * 4;
    if (base < 256 * 256) {
      const f4 v = *(const f4*)(W1 + base);
      u2 o; o.x = pack2(v.x, v.y); o.y = pack2(v.z, v.w);
      *(u2*)(W1b + base) = o;
    }
  } else {
    const int p = (b - PREP_W1_BLOCKS) * 256 + threadIdx.x;
    if (p >= P) return;
    const int v = tids[p];
    const int prev = (p == 0) ? -1 : tids[p - 1];
    for (int e = prev + 1; e <= v; ++e) ptr[e] = p;
    if (p == P - 1) {
      for (int e = v + 1; e <= E; ++e) ptr[e] = P;
    }
  }
}

// H = x @ W1^T (bf16 out). 64 nodes/block, 256 threads.
__global__ __launch_bounds__(256) void gemm_h(
    const float* __restrict__ x,
    const ushort* __restrict__ W1b,
    ushort* __restrict__ Hb,
    int N)
{
  __shared__ __align__(16) ushort Zb[64 * 256];   // 32 KB bf16 x-tile, XOR-swizzled
  const int tid  = threadIdx.x;
  const int wid  = tid >> 6;            // 0..3
  const int lane = tid & 63;
  const int l15  = lane & 15;
  const int l4   = lane >> 4;
  const int nb   = blockIdx.x * 64;     // tile's first node

  // ---- stage f32 x tile -> bf16 swizzled LDS (conversion fused here) ----
#pragma unroll
  for (int i = 0; i < 8; ++i) {
    const int off = i * 8192 + tid * 32;          // f32 byte offset in tile
    const int row = off >> 10;                    // node row 0..63
    const int src_node = min(nb + row, N - 1);    // clamp tail (dup reads ok)
    const float* sp = x + (size_t)src_node * 256 + ((off & 1023) >> 2);
    const f4 v0 = __builtin_nontemporal_load((const f4*)sp);
    const f4 v1 = __builtin_nontemporal_load((const f4*)(sp + 4));
    u4 o;
    o.x = pack2(v0.x, v0.y); o.y = pack2(v0.z, v0.w);
    o.z = pack2(v1.x, v1.y); o.w = pack2(v1.z, v1.w);
    const int dst = row * 512 + ((off & 1023) >> 1);   // bf16 byte offset
    *(u4*)((char*)Zb + (dst ^ ((row & 7) << 4))) = o;
  }
  __syncthreads();

  // ---- MFMA: C[node][h], wave owns h in [64*wid, +64) (R7-mlp verbatim) ----
  const int n0 = wid * 64;
  f32x4 acc[4][4];
#pragma unroll
  for (int mt = 0; mt < 4; ++mt)
#pragma unroll
    for (int nt = 0; nt < 4; ++nt)
      acc[mt][nt] = (f32x4){0.f, 0.f, 0.f, 0.f};

#pragma unroll
  for (int kk = 0; kk < 8; ++kk) {
    bf16x8 a[4];
#pragma unroll
    for (int mt = 0; mt < 4; ++mt) {
      const int row = mt * 16 + l15;
      const int raddr = row * 512 + kk * 64 + l4 * 16;
      a[mt] = *(const bf16x8*)((const char*)Zb + (raddr ^ ((row & 7) << 4)));
    }
#pragma unroll
    for (int nt = 0; nt < 4; ++nt) {
      const int h = n0 + nt * 16 + l15;
      const bf16x8 b = *(const bf16x8*)(W1b + (size_t)h * 256 + kk * 32 + l4 * 8);
#pragma unroll
      for (int mt = 0; mt < 4; ++mt)
        acc[mt][nt] = __builtin_amdgcn_mfma_f32_16x16x32_bf16(a[mt], b, acc[mt][nt], 0, 0, 0);
    }
  }

  // ---- store H bf16; C layout: row = mt*16 + l4*4 + r, col = n0+nt*16+l15 --
  if (nb + 64 <= N) {
#pragma unroll
    for (int mt = 0; mt < 4; ++mt)
#pragma unroll
      for (int r = 0; r < 4; ++r) {
        const size_t rowoff = (size_t)(nb + mt * 16 + l4 * 4 + r) * 256;
#pragma unroll
        for (int nt = 0; nt < 4; ++nt)
          Hb[rowoff + n0 + nt * 16 + l15] = f2bf(acc[mt][nt][r]);
      }
  } else {
#pragma unroll
    for (int mt = 0; mt < 4; ++mt)
#pragma unroll
      for (int r = 0; r < 4; ++r) {
        const int node = nb + mt * 16 + l4 * 4 + r;
        if (node < N) {
          const size_t rowoff = (size_t)node * 256;
#pragma unroll
          for (int nt = 0; nt < 4; ++nt)
            Hb[rowoff + n0 + nt * 16 + l15] = f2bf(acc[mt][nt][r]);
        }
      }
  }
}

// R7 gather engine + fused layer-2 epilogue. out[e] = sigmoid(W2.relu(sum+b1)+b2)
__global__ __launch_bounds__(128, 8) void gather_out(
    const ushort* __restrict__ Hb,
    const int* __restrict__ tnodes,
    const int* __restrict__ ptr,
    const float* __restrict__ b1,
    const float* __restrict__ W2,
    const float* __restrict__ b2,
    float* __restrict__ out,
    int E)
{
  const int lane = threadIdx.x & 63;
  const int wid  = threadIdx.x >> 6;             // 0..1
  const int e0   = blockIdx.x * 16 + wid * 8;    // this wave's 8 segments
  if (e0 >= E) return;
  const int nseg = min(8, E - e0);

  int bnd = 0;
  if (lane <= 8) bnd = ptr[min(e0 + lane, E)];   // bounds for segs e0..e0+8
  const int plo = __builtin_amdgcn_readfirstlane(__shfl(bnd, 0));
  const int phi = __builtin_amdgcn_readfirstlane(__shfl(bnd, nseg));
  const int total = phi - plo;                   // SGPR

  // per-lane epilogue coefficients: this lane owns cols lane*4 .. lane*4+3
  const int c0 = lane * 4;
  const float b1v0 = b1[c0], b1v1 = b1[c0 + 1], b1v2 = b1[c0 + 2], b1v3 = b1[c0 + 3];
  const float w2v0 = W2[c0], w2v1 = W2[c0 + 1], w2v2 = W2[c0 + 2], w2v3 = W2[c0 + 3];
  const float b2v = b2[0];

  const char* xbB = (const char*)Hb;
  const int lb = lane * 8;                       // byte offset within 512B row

  float a0 = 0.f, a1 = 0.f, a2 = 0.f, a3 = 0.f;
  int s = 0;
  int hi_s = __builtin_amdgcn_readfirstlane(__shfl(bnd, 1));

#define FLUSHOUT()                                                            \
  {                                                                           \
    float p = w2v0 * fmaxf(a0 + b1v0, 0.f);                                   \
    p = fmaf(w2v1, fmaxf(a1 + b1v1, 0.f), p);                                 \
    p = fmaf(w2v2, fmaxf(a2 + b1v2, 0.f), p);                                 \
    p = fmaf(w2v3, fmaxf(a3 + b1v3, 0.f), p);                                 \
    p += __shfl_xor(p, 1);  p += __shfl_xor(p, 2);                            \
    p += __shfl_xor(p, 4);  p += __shfl_xor(p, 8);                            \
    p += __shfl_xor(p, 16); p += __shfl_xor(p, 32);                           \
    if (lane == 0) out[e0 + s] = 1.f / (1.f + expf(-(p + b2v)));              \
    a0 = a1 = a2 = a3 = 0.f;                                                  \
  }
#define FLUSHCHK(PCUR)                                                        \
  while ((PCUR) >= hi_s) {            /* wave-uniform segment flush */        \
    FLUSHOUT()                                                                \
    ++s; hi_s = __builtin_amdgcn_readfirstlane(__shfl(bnd, min(s + 1, 8)));   \
  }
#define ACCV(V)                                                               \
  a0 += __uint_as_float((V).x << 16);                                         \
  a1 += __uint_as_float((V).x & 0xffff0000u);                                 \
  a2 += __uint_as_float((V).y << 16);                                         \
  a3 += __uint_as_float((V).y & 0xffff0000u);

  if (total > 0) {
    const int tmax = total - 1;
    u2 va[8], vb[8];
    // prologue: fill both banks; indices wave-uniform -> tnodes via s_load
#pragma unroll
    for (int k = 0; k < 8; ++k) {
      const int p = plo + min(k, tmax);
      va[k] = *(const u2*)(xbB + (size_t)tnodes[p] * 512 + lb);
    }
#pragma unroll
    for (int k = 0; k < 8; ++k) {
      const int p = plo + min(8 + k, tmax);
      vb[k] = *(const u2*)(xbB + (size_t)tnodes[p] * 512 + lb);
    }

    for (int j = 0; j < total; j += 16) {
      // consume bank A (pairs j..j+8)
#pragma unroll
      for (int k = 0; k < 8; ++k) {
        const int pc = j + k;
        if (pc < total) { FLUSHCHK(plo + pc) ACCV(va[k]) }
      }
      // refill bank A for pairs [j+16, j+24)
#pragma unroll
      for (int k = 0; k < 8; ++k) {
        const int p = plo + min(j + 16 + k, tmax);
        va[k] = *(const u2*)(xbB + (size_t)tnodes[p] * 512 + lb);
      }
      // consume bank B (pairs j+8..j+16)
#pragma unroll
      for (int k = 0; k < 8; ++k) {
        const int pc = j + 8 + k;
        if (pc < total) { FLUSHCHK(plo + pc) ACCV(vb[k]) }
      }
      // refill bank B for pairs [j+24, j+32)
#pragma unroll
      for (int k = 0; k < 8; ++k) {
        const int p = plo + min(j + 24 + k, tmax);
        vb[k] = *(const u2*)(xbB + (size_t)tnodes[p] * 512 + lb);
      }
    }
  }
  // flush remaining segments (incl. trailing empties)
  while (s < nseg) { FLUSHOUT() ++s; }
#undef FLUSHCHK
#undef FLUSHOUT
#undef ACCV
}

// ---------------- R4 fused fallback (ws too small for split path) ----------
__global__ __launch_bounds__(256, 4) void henn_main(
    const float* __restrict__ x,
    const int* __restrict__ tnodes,
    const int* __restrict__ ptr,
    const ushort* __restrict__ W1b,
    const float* __restrict__ b1,
    const float* __restrict__ W2,
    const float* __restrict__ b2,
    float* __restrict__ out,
    int E)
{
  __shared__ __align__(16) ushort Zb[64 * 256];
  const int tid  = threadIdx.x;
  const int wid  = tid >> 6;
  const int lane = tid & 63;
  const int l15  = lane & 15;
  const int l4   = lane >> 4;
  const int e0   = blockIdx.x * 64;

  int bidx = e0 + wid * 16 + lane;
  int bnd = 0;
  if (lane < 17) bnd = ptr[min(bidx, E)];

  for (int s = 0; s < 16; ++s) {
    const int lo = __shfl(bnd, s);
    const int hi = __shfl(bnd, s + 1);
    float4 a0 = {0,0,0,0}, a1 = {0,0,0,0}, a2 = {0,0,0,0}, a3 = {0,0,0,0};
    for (int base = lo; base < hi; base += 64) {
      const int cnt = min(64, hi - base);
      const int nd = (lane < cnt) ? tnodes[base + lane] : 0;
      const int rounds = (cnt + 3) >> 2;
      for (int r = 0; r < rounds; ++r) {
        const int idx = r * 4 + l4;
        const int node = __shfl(nd, min(idx, cnt - 1));
        if (idx < cnt) {
          const float4* rowp = (const float4*)(x + (size_t)node * 256) + l15;
          const float4 v0 = rowp[0];
          const float4 v1 = rowp[16];
          const float4 v2 = rowp[32];
          const float4 v3 = rowp[48];
          a0.x += v0.x; a0.y += v0.y; a0.z += v0.z; a0.w += v0.w;
          a1.x += v1.x; a1.y += v1.y; a1.z += v1.z; a1.w += v1.w;
          a2.x += v2.x; a2.y += v2.y; a2.z += v2.z; a2.w += v2.w;
          a3.x += v3.x; a3.y += v3.y; a3.z += v3.z; a3.w += v3.w;
        }
      }
    }
    a0.x += __shfl_xor(a0.x,16); a0.y += __shfl_xor(a0.y,16); a0.z += __shfl_xor(a0.z,16); a0.w += __shfl_xor(a0.w,16);
    a0.x += __shfl_xor(a0.x,32); a0.y += __shfl_xor(a0.y,32); a0.z += __shfl_xor(a0.z,32); a0.w += __shfl_xor(a0.w,32);
    a1.x += __shfl_xor(a1.x,16); a1.y += __shfl_xor(a1.y,16); a1.z += __shfl_xor(a1.z,16); a1.w += __shfl_xor(a1.w,16);
    a1.x += __shfl_xor(a1.x,32); a1.y += __shfl_xor(a1.y,32); a1.z += __shfl_xor(a1.z,32); a1.w += __shfl_xor(a1.w,32);
    a2.x += __shfl_xor(a2.x,16); a2.y += __shfl_xor(a2.y,16); a2.z += __shfl_xor(a2.z,16); a2.w += __shfl_xor(a2.w,16);
    a2.x += __shfl_xor(a2.x,32); a2.y += __shfl_xor(a2.y,32); a2.z += __shfl_xor(a2.z,32); a2.w += __shfl_xor(a2.w,32);
    a3.x += __shfl_xor(a3.x,16); a3.y += __shfl_xor(a3.y,16); a3.z += __shfl_xor(a3.z,16); a3.w += __shfl_xor(a3.w,16);
    a3.x += __shfl_xor(a3.x,32); a3.y += __shfl_xor(a3.y,32); a3.z += __shfl_xor(a3.z,32); a3.w += __shfl_xor(a3.w,32);
    float4 m = (l4 == 0) ? a0 : (l4 == 1) ? a1 : (l4 == 2) ? a2 : a3;
    const int row = wid * 16 + s;
    ushort4 o; o.x = f2bf(m.x); o.y = f2bf(m.y); o.z = f2bf(m.z); o.w = f2bf(m.w);
    const int waddr = row * 512 + lane * 8;
    *(ushort4*)((char*)Zb + (waddr ^ ((row & 7) << 4))) = o;
  }
  __syncthreads();

  const int n0 = wid * 64;
  f32x4 acc[4][4];
#pragma unroll
  for (int mt = 0; mt < 4; ++mt)
#pragma unroll
    for (int nt = 0; nt < 4; ++nt)
      acc[mt][nt] = (f32x4){0.f, 0.f, 0.f, 0.f};
#pragma unroll
  for (int kk = 0; kk < 8; ++kk) {
    bf16x8 a[4];
#pragma unroll
    for (int mt = 0; mt < 4; ++mt) {
      const int row = mt * 16 + l15;
      const int raddr = row * 512 + kk * 64 + l4 * 16;
      a[mt] = *(const bf16x8*)((const char*)Zb + (raddr ^ ((row & 7) << 4)));
    }
#pragma unroll
    for (int nt = 0; nt < 4; ++nt) {
      const int h = n0 + nt * 16 + l15;
      const bf16x8 b = *(const bf16x8*)(W1b + (size_t)h * 256 + kk * 32 + l4 * 8);
#pragma unroll
      for (int mt = 0; mt < 4; ++mt)
        acc[mt][nt] = __builtin_amdgcn_mfma_f32_16x16x32_bf16(a[mt], b, acc[mt][nt], 0, 0, 0);
    }
  }
  __syncthreads();

  float b1h[4], w2v[4];
#pragma unroll
  for (int nt = 0; nt < 4; ++nt) {
    const int h = n0 + nt * 16 + l15;
    b1h[nt] = b1[h];
    w2v[nt] = W2[h];
  }
  float* red = (float*)Zb;
#pragma unroll
  for (int mt = 0; mt < 4; ++mt) {
#pragma unroll
    for (int r = 0; r < 4; ++r) {
      float p = 0.f;
#pragma unroll
      for (int nt = 0; nt < 4; ++nt) {
        const float y = acc[mt][nt][r] + b1h[nt];
        p = fmaf(w2v[nt], fmaxf(y, 0.f), p);
      }
      p += __shfl_xor(p, 1);
      p += __shfl_xor(p, 2);
      p += __shfl_xor(p, 4);
      p += __shfl_xor(p, 8);
      if (l15 == 0) red[wid * 64 + mt * 16 + l4 * 4 + r] = p;
    }
  }
  __syncthreads();

  if (tid < 64) {
    const int e = e0 + tid;
    if (e < E) {
      const float v = red[tid] + red[64 + tid] + red[128 + tid] + red[192 + tid] + b2[0];
      out[e] = 1.f / (1.f + expf(-v));
    }
  }
}

extern "C" void kernel_launch(void* const* d_in, const int* in_sizes, int n_in,
                              void* d_out, int out_size, void* d_ws, size_t ws_size,
                              hipStream_t stream) {
  const float* x      = (const float*)d_in[0];
  const int*   tnodes = (const int*)d_in[1];
  const int*   tids   = (const int*)d_in[2];
  const float* W1     = (const float*)d_in[3];
  const float* b1     = (const float*)d_in[4];
  const float* W2     = (const float*)d_in[5];
  const float* b2     = (const float*)d_in[6];
  (void)n_in;

  const int P       = in_sizes[1];        // 800000
  const int E       = out_size;           // 100000
  const int n_nodes = in_sizes[0] / 256;  // 100000

  const size_t OFF_W1B  = 512 * 1024;
  const size_t OFF_HB   = 1024 * 1024;
  const size_t hb_bytes = (size_t)n_nodes * 512 + 65536;
  const size_t need     = OFF_HB + hb_bytes;

  int*    seg_ptr = (int*)d_ws;
  ushort* W1b     = (ushort*)((char*)d_ws + OFF_W1B);
  ushort* Hb      = (ushort*)((char*)d_ws + OFF_HB);

  const int prep_grid = PREP_W1_BLOCKS + (P + 255) / 256;
  prep2<<<prep_grid, 256, 0, stream>>>(W1, W1b, tids, seg_ptr, P, E);

  if (ws_size >= need) {
    const int gemm_blocks = (n_nodes + 63) / 64;
    gemm_h<<<gemm_blocks, 256, 0, stream>>>(x, W1b, Hb, n_nodes);
    const int gblocks = (E + 15) / 16;
    gather_out<<<gblocks, 128, 0, stream>>>(Hb, tnodes, seg_ptr, b1, W2, b2,
                                            (float*)d_out, E);
  } else {
    const int blocks = (E + 63) / 64;
    henn_main<<<blocks, 256, 0, stream>>>(x, tnodes, seg_ptr, W1b, b1, W2, b2,
                                          (float*)d_out, E);
  }
}